// Round 6
// baseline (49.636 us; speedup 1.0000x reference)
//
#include <hip/hip_runtime.h>
#include <hip/hip_bf16.h>

#define B_SZ 256
#define N_SZ 2000
#define N_PAD 2048
#define D_SZ 512
#define C_SZ 100
#define BT 4           // batch rows per thread
#define D4 (D_SZ / 4)  // 128 float4 chunks per row
#define PF 4           // support prefetch depth (dc steps)
#define DSPLIT 4       // D split across blockIdx.z -> 4x wave occupancy
#define DQ (D4 / DSPLIT) // 32 dc per block

// ---------------------------------------------------------------------------
// Prep: one-hot labels -> class index per support sample (no atomics)
// ---------------------------------------------------------------------------
__global__ void prep_kernel(const float* __restrict__ labels,
                            int* __restrict__ idx) {
    int n = blockIdx.x * 256 + threadIdx.x;
    if (n < N_SZ) {
        const float4* row = (const float4*)(labels + (size_t)n * C_SZ); // 25 float4
        int c = 0;
#pragma unroll
        for (int j = 0; j < C_SZ / 4; ++j) {
            float4 v = row[j];
            if (v.x > 0.5f) c = 4 * j + 0;
            if (v.y > 0.5f) c = 4 * j + 1;
            if (v.z > 0.5f) c = 4 * j + 2;
            if (v.w > 0.5f) c = 4 * j + 3;
        }
        idx[n] = c;
    }
}

// ---------------------------------------------------------------------------
// Transpose support [N][D4] float4 -> [D4][N_PAD] float4 (coalesced stream)
// ---------------------------------------------------------------------------
__global__ void transpose_kernel(const float4* __restrict__ sup4,
                                 float4* __restrict__ supT4) {
    int t = blockIdx.x * 256 + threadIdx.x; // t = dc * N_PAD + n
    int dc = t >> 11;                       // / N_PAD
    int n  = t & (N_PAD - 1);
    float4 v = make_float4(0.f, 0.f, 0.f, 0.f);
    if (n < N_SZ) v = sup4[(size_t)n * D4 + dc];
    supT4[t] = v;
}

// ---------------------------------------------------------------------------
// Main. Round-5 lesson: per-iteration s_load latency exposed at only
// 2 waves/SIMD (grid-limited). Fix: 4-way D-split (blockIdx.z) -> 2048
// blocks, 8 blocks/CU, up to 8 waves/SIMD; per-wave stalls now overlap
// across waves. Partial logits go to S[z][B][N_PAD]; agg combines.
// Support stream keeps the named-register VMEM pipeline; inputs/w stay on
// the scalar pipe (wave-uniform addresses).
// ---------------------------------------------------------------------------
__global__ __launch_bounds__(256, 8) void score_kernel(
    const float4* __restrict__ inp4,   // [B][D4]
    const float4* __restrict__ supT4,  // [D4][N_PAD]
    const float4* __restrict__ w4,     // [D4]
    float* __restrict__ S)             // [DSPLIT][B][N_PAD] partial logits
{
    int tid = threadIdx.x;
    int n   = blockIdx.x * 256 + tid;
    int b0  = blockIdx.y * BT;
    int off = blockIdx.z * DQ;

    // Wave-uniform row bases -> scalar loads inside the loop
    const float4* __restrict__ a0 = inp4 + (size_t)(b0 + 0) * D4 + off;
    const float4* __restrict__ a1 = inp4 + (size_t)(b0 + 1) * D4 + off;
    const float4* __restrict__ a2 = inp4 + (size_t)(b0 + 2) * D4 + off;
    const float4* __restrict__ a3 = inp4 + (size_t)(b0 + 3) * D4 + off;
    const float4* __restrict__ wq = w4 + off;

    const float4* __restrict__ sp = supT4 + (size_t)off * N_PAD + n;

    float acc[BT] = {0.f, 0.f, 0.f, 0.f};

    auto compute = [&](int dc, const float4& sv) {
        float4 wv = wq[dc];
        float4 av;
        av = a0[dc];
        acc[0] += wv.x * fabsf(av.x - sv.x);
        acc[0] += wv.y * fabsf(av.y - sv.y);
        acc[0] += wv.z * fabsf(av.z - sv.z);
        acc[0] += wv.w * fabsf(av.w - sv.w);
        av = a1[dc];
        acc[1] += wv.x * fabsf(av.x - sv.x);
        acc[1] += wv.y * fabsf(av.y - sv.y);
        acc[1] += wv.z * fabsf(av.z - sv.z);
        acc[1] += wv.w * fabsf(av.w - sv.w);
        av = a2[dc];
        acc[2] += wv.x * fabsf(av.x - sv.x);
        acc[2] += wv.y * fabsf(av.y - sv.y);
        acc[2] += wv.z * fabsf(av.z - sv.z);
        acc[2] += wv.w * fabsf(av.w - sv.w);
        av = a3[dc];
        acc[3] += wv.x * fabsf(av.x - sv.x);
        acc[3] += wv.y * fabsf(av.y - sv.y);
        acc[3] += wv.z * fabsf(av.z - sv.z);
        acc[3] += wv.w * fabsf(av.w - sv.w);
    };

    // Manual software pipeline: PF support chunks in flight in named regs.
    float4 c0 = sp[(size_t)0 * N_PAD];
    float4 c1 = sp[(size_t)1 * N_PAD];
    float4 c2 = sp[(size_t)2 * N_PAD];
    float4 c3 = sp[(size_t)3 * N_PAD];

#pragma unroll 1
    for (int dc = 0; dc < DQ - PF; dc += PF) {
        float4 t0 = sp[(size_t)(dc + 4) * N_PAD];
        float4 t1 = sp[(size_t)(dc + 5) * N_PAD];
        float4 t2 = sp[(size_t)(dc + 6) * N_PAD];
        float4 t3 = sp[(size_t)(dc + 7) * N_PAD];
        compute(dc + 0, c0);
        compute(dc + 1, c1);
        compute(dc + 2, c2);
        compute(dc + 3, c3);
        c0 = t0; c1 = t1; c2 = t2; c3 = t3;
    }
    compute(DQ - 4, c0);
    compute(DQ - 3, c1);
    compute(DQ - 2, c2);
    compute(DQ - 1, c3);

    float* __restrict__ Sz = S + ((size_t)blockIdx.z * B_SZ + b0) * N_PAD + n;
#pragma unroll
    for (int i = 0; i < BT; ++i)
        Sz[(size_t)i * N_PAD] = acc[i]; // coalesced; pad cols never read
}

// ---------------------------------------------------------------------------
// Aggregate: one block per batch row. Sum 4 D-partials + bias -> sigmoid ->
// LDS class bins -> divide_no_nan. No global atomics, no pre-zeroing.
// ---------------------------------------------------------------------------
__global__ void agg_kernel(const float* __restrict__ S,
                           const int* __restrict__ idx,
                           const float* __restrict__ bias_p,
                           float* __restrict__ out) {
    __shared__ float sums[C_SZ];
    __shared__ float cnts[C_SZ];
    int b = blockIdx.x;
    int t = threadIdx.x;
    if (t < C_SZ) { sums[t] = 0.f; cnts[t] = 0.f; }
    __syncthreads();
    float bias = *bias_p;
    for (int n = t; n < N_SZ; n += 256) {
        float logit = bias;
#pragma unroll
        for (int z = 0; z < DSPLIT; ++z)
            logit += S[((size_t)z * B_SZ + b) * N_PAD + n];
        float s = 1.0f / (1.0f + __expf(-logit));
        int c = idx[n];
        atomicAdd(&sums[c], s);
        atomicAdd(&cnts[c], 1.0f);
    }
    __syncthreads();
    if (t < C_SZ) {
        float cnt = cnts[t];
        out[(size_t)b * C_SZ + t] = (cnt != 0.f) ? sums[t] / cnt : 0.f;
    }
}

extern "C" void kernel_launch(void* const* d_in, const int* in_sizes, int n_in,
                              void* d_out, int out_size, void* d_ws, size_t ws_size,
                              hipStream_t stream) {
    const float* inputs  = (const float*)d_in[0]; // [B, D]
    const float* support = (const float*)d_in[1]; // [N, D]
    const float* labels  = (const float*)d_in[2]; // [N, C]
    const float* w       = (const float*)d_in[3]; // [D]
    const float* bias    = (const float*)d_in[4]; // [1]
    float* out = (float*)d_out;                   // [B, C]

    // Workspace: idx[2048] @0 (8KB, fully written by prep), pad to 16KB,
    // supT4 @16KB (4MB), S @16KB+4MB (DSPLIT*2MB = 8MB). No zeroing needed.
    int*    idx   = (int*)d_ws;
    float4* supT4 = (float4*)((char*)d_ws + 16384);
    float*  S     = (float*)((char*)d_ws + 16384 + (size_t)D4 * N_PAD * sizeof(float4));

    prep_kernel<<<dim3((N_SZ + 255) / 256), dim3(256), 0, stream>>>(labels, idx);

    transpose_kernel<<<dim3(D4 * N_PAD / 256), dim3(256), 0, stream>>>(
        (const float4*)support, supT4);

    dim3 grid(N_PAD / 256, B_SZ / BT, DSPLIT); // 8 x 64 x 4 = 2048 blocks
    score_kernel<<<grid, dim3(256), 0, stream>>>(
        (const float4*)inputs, supT4, (const float4*)w, S);

    agg_kernel<<<dim3(B_SZ), dim3(256), 0, stream>>>(S, idx, bias, out);
}